// Round 5
// baseline (3647.989 us; speedup 1.0000x reference)
//
#include <hip/hip_runtime.h>
#include <hip/hip_bf16.h>

#define N_ROWS 131072
#define DIM    768
#define K_C    2000
#define K_PAD  2048
#define TAU    2e-2f
#define LISTCAP 4096

typedef _Float16 f16;
typedef _Float16 f16x4 __attribute__((ext_vector_type(4)));
typedef _Float16 f16x8 __attribute__((ext_vector_type(8)));
typedef float    f32x4 __attribute__((ext_vector_type(4)));

// ---- workspace layout (bytes) ----
#define OFF_CTL  3145728    // cTl  [2048][768] f16
#define OFF_CN   6291456    // cn   [2048] f32
#define OFF_XN   6299648    // xn   [131072] f32
#define OFF_PMIN 6823936    // pmin [16][131072] f32
#define OFF_PSEC 15212544   // psec [16][131072] f32
#define OFF_PIDX 23601152   // pidx [16][131072] i32
#define OFF_CNT  31989760   // counter (4B, padded)
#define OFF_LIST 31990016   // list [4096] i32
#define OFF_CN64 32006400   // cn64 [2048] f64  -> total ~32.02 MB

static __device__ __forceinline__ void gload16(const void* g, void* l) {
  __builtin_amdgcn_global_load_lds(
      (const __attribute__((address_space(1))) unsigned int*)g,
      (__attribute__((address_space(3))) unsigned int*)l, 16, 0, 0);
}

// K1: centroid transpose + fp16 hi/lo split (lo scaled 4096) + fp32 c_norm
// (np axis-0 order: sequential over d) + fp64 c_norm for the exact recheck.
__global__ void prep_centroids(const float* __restrict__ cent,
                               f16* __restrict__ cTh, f16* __restrict__ cTl,
                               float* __restrict__ cn, double* __restrict__ cn64) {
#pragma clang fp contract(off)
  int k = blockIdx.x * 256 + threadIdx.x;  // 0..2047
  float s = 0.0f;
  double s64 = 0.0;
  for (int d = 0; d < DIM; ++d) {
    float c = (k < K_C) ? cent[d * K_C + k] : 0.0f;
    f16 h = (f16)c;
    f16 l = (f16)((c - (float)h) * 4096.0f);
    cTh[k * DIM + d] = h;
    cTl[k * DIM + d] = l;
    float sq = c * c;
    s = s + sq;
    s64 += (double)c * (double)c;
  }
  cn[k] = (k < K_C) ? s : INFINITY;
  cn64[k] = (k < K_C) ? s64 : (double)INFINITY;
}

// K2: x_norm per numpy FLOAT_pairwise_sum(768) scalar semantics (feeds the
// fp32 main path / margins only; the recheck recomputes xn in fp64).
__global__ __launch_bounds__(256) void xnorm_kernel(const float* __restrict__ x,
                                                    float* __restrict__ xn) {
#pragma clang fp contract(off)
  __shared__ __align__(16) float buf[16 * DIM];  // 48 KB, 16 rows
  int row0 = blockIdx.x * 16;
  int tid = threadIdx.x;
  const f32x4* src = (const f32x4*)(x + (size_t)row0 * DIM);
  f32x4* dst = (f32x4*)buf;
#pragma unroll
  for (int c = 0; c < 12; ++c) dst[c * 256 + tid] = src[c * 256 + tid];
  __syncthreads();
  int w = tid >> 6, lane = tid & 63;
  int b = lane >> 3, j = lane & 7;
#pragma unroll
  for (int rr = 0; rr < 4; ++rr) {
    int r = w * 4 + rr;
    const float* a = buf + r * DIM + 96 * b + j;
    float v0 = a[0];
    float acc = v0 * v0;
#pragma unroll
    for (int t = 1; t < 12; ++t) {
      float q = a[8 * t];
      float s = q * q;
      acc = acc + s;
    }
    float v = acc;
    { float o = __shfl_xor(v, 1);  v = v + o; }
    { float o = __shfl_xor(v, 2);  v = v + o; }
    { float o = __shfl_xor(v, 4);  v = v + o; }
    { float o = __shfl_xor(v, 8);  v = v + o; }
    { float o = __shfl_xor(v, 16); v = v + o; }
    { float o = __shfl_xor(v, 32); v = v + o; }
    if (lane == 0) xn[row0 + r] = v;
  }
}

// K3: split-fp16 MFMA GEMM + fused per-panel best/second/argmin.
__global__ __launch_bounds__(256, 2) void kmeans_main(
    const float* __restrict__ x, const f16* __restrict__ cTh,
    const f16* __restrict__ cTl, const float* __restrict__ cn,
    const float* __restrict__ xn, float* __restrict__ pmin,
    float* __restrict__ psec, int* __restrict__ pidx) {
  __shared__ __align__(16) f16 lds[32768];  // 64 KiB
  f16* sAh = lds;
  f16* sAl = lds + 8192;
  f16* sBh = lds + 16384;
  f16* sBl = lds + 24576;

  int d0 = blockIdx.x;
  int g  = (d0 & 7) * 2048 + (d0 >> 3);  // XCD-grouped
  int pb = g & 15;
  int rb = g >> 4;

  int tid  = threadIdx.x;
  int w    = tid >> 6;
  int lane = tid & 63;
  int wrow = (w >> 1) * 64;
  int wcol = (w & 1) * 64;

  f32x4 acc[4][4] = {};
  f32x4 accx[4][4] = {};

  f32x4 av[8];
#pragma unroll
  for (int i = 0; i < 8; ++i) {
    int e = i * 256 + tid, row = e >> 4, ch = e & 15;
    av[i] = *(const f32x4*)(x + (size_t)(rb * 128 + row) * DIM + ch * 4);
  }

  for (int kt = 0; kt < 12; ++kt) {
    __syncthreads();
#pragma unroll
    for (int i = 0; i < 8; ++i) {
      int e = i * 256 + tid, row = e >> 4, ch = e & 15;
      f16x4 hv, lv;
#pragma unroll
      for (int c = 0; c < 4; ++c) {
        float v = av[i][c];
        f16 h = (f16)v;
        hv[c] = h;
        lv[c] = (f16)((v - (float)h) * 4096.0f);
      }
      int boff = row * 128 + ((((ch >> 1) ^ (row & 7)) << 4)) + ((ch & 1) << 3);
      *(f16x4*)((char*)sAh + boff) = hv;
      *(f16x4*)((char*)sAl + boff) = lv;
    }
#pragma unroll
    for (int i = 0; i < 4; ++i) {
      int q = w * 4 + i;
      int s0 = q * 1024 + lane * 16;
      int row = s0 >> 7;
      int slot = ((s0 >> 4) & 7) ^ (row & 7);
      size_t goff = (size_t)(pb * 128 + row) * DIM + kt * 64 + slot * 8;
      gload16(cTh + goff, (char*)sBh + q * 1024);
      gload16(cTl + goff, (char*)sBl + q * 1024);
    }
    if (kt < 11) {
#pragma unroll
      for (int i = 0; i < 8; ++i) {
        int e = i * 256 + tid, row = e >> 4, ch = e & 15;
        av[i] = *(const f32x4*)(x + (size_t)(rb * 128 + row) * DIM +
                                (kt + 1) * 64 + ch * 4);
      }
    }
    __syncthreads();

#pragma unroll
    for (int k32 = 0; k32 < 2; ++k32) {
      f16x8 ah[4], al[4], bh[4], bl[4];
      int ksel = lane >> 4;
      int rsel = lane & 15;
#pragma unroll
      for (int m = 0; m < 4; ++m) {
        int row = wrow + m * 16 + rsel;
        int boff = row * 128 + (((k32 * 4 + ksel) ^ (row & 7)) << 4);
        ah[m] = *(const f16x8*)((const char*)sAh + boff);
        al[m] = *(const f16x8*)((const char*)sAl + boff);
      }
#pragma unroll
      for (int n = 0; n < 4; ++n) {
        int row = wcol + n * 16 + rsel;
        int boff = row * 128 + (((k32 * 4 + ksel) ^ (row & 7)) << 4);
        bh[n] = *(const f16x8*)((const char*)sBh + boff);
        bl[n] = *(const f16x8*)((const char*)sBl + boff);
      }
#pragma unroll
      for (int m = 0; m < 4; ++m)
#pragma unroll
        for (int n = 0; n < 4; ++n) {
          acc[m][n] =
              __builtin_amdgcn_mfma_f32_16x16x32_f16(ah[m], bh[n], acc[m][n], 0, 0, 0);
          accx[m][n] =
              __builtin_amdgcn_mfma_f32_16x16x32_f16(ah[m], bl[n], accx[m][n], 0, 0, 0);
          accx[m][n] =
              __builtin_amdgcn_mfma_f32_16x16x32_f16(al[m], bh[n], accx[m][n], 0, 0, 0);
        }
    }
  }

  __syncthreads();
  float* lv = (float*)lds;                 // [2][128]
  float* lsv = (float*)lds + 256;          // [2][128]
  int*   li = (int*)((float*)lds + 512);   // [2][128]

  int rsel = lane & 15;
  int colbase = pb * 128 + wcol + rsel;
  float cnv[4];
#pragma unroll
  for (int n = 0; n < 4; ++n) cnv[n] = cn[colbase + n * 16];
  int g4 = (lane >> 4) * 4;

#pragma unroll
  for (int m = 0; m < 4; ++m) {
#pragma unroll
    for (int j = 0; j < 4; ++j) {
      int trow = wrow + m * 16 + g4 + j;
      float xv = xn[rb * 128 + trow];
      float v1 = 0.0f, v2 = INFINITY;
      int i1 = 0;
#pragma unroll
      for (int n = 0; n < 4; ++n) {
        float dot = acc[m][n][j] + accx[m][n][j] * (1.0f / 4096.0f);
        float dd = (xv - 2.0f * dot) + cnv[n];
        int ci = colbase + n * 16;
        if (n == 0) { v1 = dd; i1 = ci; }
        else if (dd < v1) { v2 = v1; v1 = dd; i1 = ci; }
        else { v2 = fminf(v2, dd); }
      }
#pragma unroll
      for (int off = 1; off < 16; off <<= 1) {
        float ov1 = __shfl_xor(v1, off);
        float ov2 = __shfl_xor(v2, off);
        int oi1 = __shfl_xor(i1, off);
        if (ov1 < v1 || (ov1 == v1 && oi1 < i1)) {
          v2 = fminf(v1, ov2); v1 = ov1; i1 = oi1;
        } else {
          v2 = fminf(v2, ov1);
        }
      }
      if ((lane & 15) == 0) {
        lv[(w & 1) * 128 + trow] = v1;
        lsv[(w & 1) * 128 + trow] = v2;
        li[(w & 1) * 128 + trow] = i1;
      }
    }
  }
  __syncthreads();
  if (tid < 128) {
    float a1 = lv[tid], a2 = lsv[tid];
    int aj = li[tid];
    float b1 = lv[128 + tid], b2 = lsv[128 + tid];
    int bj = li[128 + tid];
    float v1, v2; int i1;
    if (b1 < a1 || (b1 == a1 && bj < aj)) { v1 = b1; i1 = bj; v2 = fminf(b2, a1); }
    else { v1 = a1; i1 = aj; v2 = fminf(a2, b1); }
    size_t o = (size_t)pb * N_ROWS + rb * 128 + tid;
    pmin[o] = v1;
    psec[o] = v2;
    pidx[o] = i1;
  }
}

// K4: merge 16 panel triples; write argmin; flag ambiguous rows (margin < TAU).
__global__ void merge_detect(const float* __restrict__ pmin,
                             const float* __restrict__ psec,
                             const int* __restrict__ pidx, int* __restrict__ out,
                             int* __restrict__ list, int* __restrict__ counter) {
  int n = blockIdx.x * 256 + threadIdx.x;
  float v1 = INFINITY, v2 = INFINITY;
  int i1 = 0x7fffffff;
  for (int p = 0; p < 16; ++p) {
    float a1 = pmin[(size_t)p * N_ROWS + n];
    float a2 = psec[(size_t)p * N_ROWS + n];
    int aj = pidx[(size_t)p * N_ROWS + n];
    if (a1 < v1 || (a1 == v1 && aj < i1)) {
      v2 = fminf(v1, a2); v1 = a1; i1 = aj;
    } else {
      v2 = fminf(v2, a1);
    }
  }
  out[n] = i1;
  if (v2 - v1 < TAU) {
    int idx = atomicAdd(counter, 1);
    if (idx < LISTCAP) list[idx] = n;
  }
}

// K5: float64 exact recheck for ambiguous rows — true distances, no
// fp32 quantization. xn recomputed in fp64; cn64 from K1; fp64 fma dot.
__global__ __launch_bounds__(256) void exact_recheck64(
    const float* __restrict__ x, const float* __restrict__ cent,
    const double* __restrict__ cn64, const int* __restrict__ list,
    const int* __restrict__ counter, int* __restrict__ out) {
  __shared__ double xrow[DIM];   // 6 KB
  __shared__ double rv[256];
  __shared__ int ri[256];
  int b = blockIdx.x;
  if (b >= counter[0]) return;
  int n = list[b];
  int tid = threadIdx.x;
  double part = 0.0;
  for (int d = tid; d < DIM; d += 256) {
    double v = (double)x[(size_t)n * DIM + d];
    xrow[d] = v;
    part += v * v;
  }
  rv[tid] = part;
  __syncthreads();
  for (int s = 128; s > 0; s >>= 1) {
    if (tid < s) rv[tid] += rv[tid + s];
    __syncthreads();
  }
  double xn64 = rv[0];
  __syncthreads();
  double acc[8] = {0, 0, 0, 0, 0, 0, 0, 0};
  for (int d = 0; d < DIM; ++d) {
    double xv = xrow[d];
    const float* cp = cent + (size_t)d * K_C;
#pragma unroll
    for (int kk = 0; kk < 8; ++kk) {
      int k = tid + kk * 256;
      if (k < K_C) acc[kk] = fma(xv, (double)cp[k], acc[kk]);
    }
  }
  double bv = (double)INFINITY;
  int bi = 0x7fffffff;
#pragma unroll
  for (int kk = 0; kk < 8; ++kk) {
    int k = tid + kk * 256;
    if (k < K_C) {
      double dd = (xn64 - 2.0 * acc[kk]) + cn64[k];
      if (dd < bv) { bv = dd; bi = k; }  // k ascending -> first index kept
    }
  }
  rv[tid] = bv;
  ri[tid] = bi;
  __syncthreads();
  for (int s = 128; s > 0; s >>= 1) {
    if (tid < s) {
      double ov = rv[tid + s];
      int oi = ri[tid + s];
      if (ov < rv[tid] || (ov == rv[tid] && oi < ri[tid])) {
        rv[tid] = ov; ri[tid] = oi;
      }
    }
    __syncthreads();
  }
  if (tid == 0) out[n] = ri[0];
}

extern "C" void kernel_launch(void* const* d_in, const int* in_sizes, int n_in,
                              void* d_out, int out_size, void* d_ws, size_t ws_size,
                              hipStream_t stream) {
  const float* x = (const float*)d_in[0];
  const float* cent = (const float*)d_in[1];
  char* ws = (char*)d_ws;
  f16* cTh = (f16*)ws;
  f16* cTl = (f16*)(ws + OFF_CTL);
  float* cn = (float*)(ws + OFF_CN);
  float* xn = (float*)(ws + OFF_XN);
  float* pmin = (float*)(ws + OFF_PMIN);
  float* psec = (float*)(ws + OFF_PSEC);
  int* pidx = (int*)(ws + OFF_PIDX);
  int* counter = (int*)(ws + OFF_CNT);
  int* list = (int*)(ws + OFF_LIST);
  double* cn64 = (double*)(ws + OFF_CN64);

  hipMemsetAsync(counter, 0, 4, stream);
  prep_centroids<<<8, 256, 0, stream>>>(cent, cTh, cTl, cn, cn64);
  xnorm_kernel<<<N_ROWS / 16, 256, 0, stream>>>(x, xn);
  kmeans_main<<<16384, 256, 0, stream>>>(x, cTh, cTl, cn, xn, pmin, psec, pidx);
  merge_detect<<<N_ROWS / 256, 256, 0, stream>>>(pmin, psec, pidx, (int*)d_out,
                                                 list, counter);
  exact_recheck64<<<LISTCAP, 256, 0, stream>>>(x, cent, cn64, list, counter,
                                               (int*)d_out);
}

// Round 6
// 3388.095 us; speedup vs baseline: 1.0767x; 1.0767x over previous
//
#include <hip/hip_runtime.h>
#include <hip/hip_bf16.h>

#define N_ROWS 131072
#define DIM    768
#define K_C    2000
#define K_PAD  2048
#define TAU    2e-2f
#define LISTCAP 4096

typedef _Float16 f16;
typedef _Float16 f16x4 __attribute__((ext_vector_type(4)));
typedef _Float16 f16x8 __attribute__((ext_vector_type(8)));
typedef float    f32x4 __attribute__((ext_vector_type(4)));

// ---- workspace layout (bytes) ----
#define OFF_CTL  3145728    // cTl  [2048][768] f16
#define OFF_CN   6291456    // cn   [2048] f32
#define OFF_XN   6299648    // xn   [131072] f32
#define OFF_PMIN 6823936    // pmin [16][131072] f32
#define OFF_PSEC 15212544   // psec [16][131072] f32
#define OFF_PIDX 23601152   // pidx [16][131072] i32
#define OFF_CNT  31989760   // counter (4B, padded)
#define OFF_LIST 31990016   // list [4096] i32
#define OFF_CN64 32006400   // cn64 [2048] f64
#define OFF_XH   32022784   // xh [131072][768] f16 (PRE path)
#define OFF_XL   233349376  // xl [131072][768] f16 (PRE path)
#define WS_NEED  434675968ULL

static __device__ __forceinline__ void gload16(const void* g, void* l) {
  __builtin_amdgcn_global_load_lds(
      (const __attribute__((address_space(1))) unsigned int*)g,
      (__attribute__((address_space(3))) unsigned int*)l, 16, 0, 0);
}

static __device__ __forceinline__ void split16(float v, f16& h, f16& l) {
  h = (f16)v;
  l = (f16)((v - (float)h) * 4096.0f);
}

// K1a: c_norm only (np axis-0 order: sequential over d; square rounded first)
// + fp64 c_norm for the exact recheck. Coalesced loads, no scatter stores.
__global__ void prep_cn(const float* __restrict__ cent, float* __restrict__ cn,
                        double* __restrict__ cn64) {
#pragma clang fp contract(off)
  int k = blockIdx.x * 256 + threadIdx.x;  // 0..2047
  float s = 0.0f;
  double s64 = 0.0;
  for (int d = 0; d < DIM; ++d) {
    float c = (k < K_C) ? cent[d * K_C + k] : 0.0f;
    float sq = c * c;
    s = s + sq;
    s64 += (double)c * (double)c;
  }
  cn[k] = (k < K_C) ? s : INFINITY;
  cn64[k] = (k < K_C) ? s64 : (double)INFINITY;
}

// K1b: centroid transpose + f16 hi/lo split via 64x64 LDS tile.
// Loads coalesced over k; stores coalesced over d (128B/wave).
__global__ __launch_bounds__(256) void prep_ct(const float* __restrict__ cent,
                                               f16* __restrict__ cTh,
                                               f16* __restrict__ cTl) {
  __shared__ float ld[64][65];
  int k0 = blockIdx.x * 64;  // 32 blocks
  int d0 = blockIdx.y * 64;  // 12 blocks
  int tid = threadIdx.x;
#pragma unroll
  for (int it = 0; it < 16; ++it) {
    int idx = it * 256 + tid;
    int dd = idx >> 6, kk = idx & 63;
    int k = k0 + kk;
    ld[dd][kk] = (k < K_C) ? cent[(size_t)(d0 + dd) * K_C + k] : 0.0f;
  }
  __syncthreads();
#pragma unroll
  for (int it = 0; it < 16; ++it) {
    int idx = it * 256 + tid;
    int kk = idx >> 6, dd = idx & 63;
    float v = ld[dd][kk];
    f16 h, l;
    split16(v, h, l);
    size_t o = (size_t)(k0 + kk) * DIM + d0 + dd;
    cTh[o] = h;
    cTl[o] = l;
  }
}

// K1c: x -> f16 hi/lo (PRE path). 8 floats/thread, all coalesced.
__global__ __launch_bounds__(256) void prep_x(const float* __restrict__ x,
                                              f16* __restrict__ xh,
                                              f16* __restrict__ xl) {
  size_t t = (size_t)blockIdx.x * 256 + threadIdx.x;
  const f32x4* src = (const f32x4*)(x + t * 8);
  f32x4 a = src[0], b = src[1];
  f16x8 hv, lv;
#pragma unroll
  for (int j = 0; j < 4; ++j) {
    f16 h, l;
    split16(a[j], h, l);
    hv[j] = h; lv[j] = l;
    split16(b[j], h, l);
    hv[4 + j] = h; lv[4 + j] = l;
  }
  *(f16x8*)(xh + t * 8) = hv;
  *(f16x8*)(xl + t * 8) = lv;
}

// K2: x_norm per numpy FLOAT_pairwise_sum(768) scalar semantics (feeds the
// fp32 main path / margins only; the recheck recomputes xn in fp64).
__global__ __launch_bounds__(256) void xnorm_kernel(const float* __restrict__ x,
                                                    float* __restrict__ xn) {
#pragma clang fp contract(off)
  __shared__ __align__(16) float buf[16 * DIM];  // 48 KB, 16 rows
  int row0 = blockIdx.x * 16;
  int tid = threadIdx.x;
  const f32x4* src = (const f32x4*)(x + (size_t)row0 * DIM);
  f32x4* dst = (f32x4*)buf;
#pragma unroll
  for (int c = 0; c < 12; ++c) dst[c * 256 + tid] = src[c * 256 + tid];
  __syncthreads();
  int w = tid >> 6, lane = tid & 63;
  int b = lane >> 3, j = lane & 7;
#pragma unroll
  for (int rr = 0; rr < 4; ++rr) {
    int r = w * 4 + rr;
    const float* a = buf + r * DIM + 96 * b + j;
    float v0 = a[0];
    float acc = v0 * v0;
#pragma unroll
    for (int t = 1; t < 12; ++t) {
      float q = a[8 * t];
      float s = q * q;
      acc = acc + s;
    }
    float v = acc;
    { float o = __shfl_xor(v, 1);  v = v + o; }
    { float o = __shfl_xor(v, 2);  v = v + o; }
    { float o = __shfl_xor(v, 4);  v = v + o; }
    { float o = __shfl_xor(v, 8);  v = v + o; }
    { float o = __shfl_xor(v, 16); v = v + o; }
    { float o = __shfl_xor(v, 32); v = v + o; }
    if (lane == 0) xn[row0 + r] = v;
  }
}

// K3: split-fp16 MFMA GEMM + fused per-panel best/second/argmin.
// PRE=1: A staged via global_load_lds from precomputed xh/xl (no VALU
// conversion in the K-loop). PRE=0: r5 fallback (reg-stage + convert).
template <int PRE>
__global__ __launch_bounds__(256, 2) void kmeans_main(
    const float* __restrict__ x, const f16* __restrict__ xh,
    const f16* __restrict__ xl, const f16* __restrict__ cTh,
    const f16* __restrict__ cTl, const float* __restrict__ cn,
    const float* __restrict__ xn, float* __restrict__ pmin,
    float* __restrict__ psec, int* __restrict__ pidx) {
  __shared__ __align__(16) f16 lds[32768];  // 64 KiB
  f16* sAh = lds;
  f16* sAl = lds + 8192;
  f16* sBh = lds + 16384;
  f16* sBl = lds + 24576;

  int d0 = blockIdx.x;
  int g  = (d0 & 7) * 2048 + (d0 >> 3);  // XCD-grouped
  int pb = g & 15;
  int rb = g >> 4;

  int tid  = threadIdx.x;
  int w    = tid >> 6;
  int lane = tid & 63;
  int wrow = (w >> 1) * 64;
  int wcol = (w & 1) * 64;

  f32x4 acc[4][4] = {};
  f32x4 accx[4][4] = {};

  f32x4 av[8];
  if constexpr (!PRE) {
#pragma unroll
    for (int i = 0; i < 8; ++i) {
      int e = i * 256 + tid, row = e >> 4, ch = e & 15;
      av[i] = *(const f32x4*)(x + (size_t)(rb * 128 + row) * DIM + ch * 4);
    }
  }

  for (int kt = 0; kt < 12; ++kt) {
    __syncthreads();
    if constexpr (PRE) {
      // A + B both via global_load_lds: linear LDS dest, inverse-swizzled src
#pragma unroll
      for (int i = 0; i < 4; ++i) {
        int q = w * 4 + i;
        int s0 = q * 1024 + lane * 16;
        int row = s0 >> 7;
        int slot = ((s0 >> 4) & 7) ^ (row & 7);
        size_t goffA = (size_t)(rb * 128 + row) * DIM + kt * 64 + slot * 8;
        size_t goffB = (size_t)(pb * 128 + row) * DIM + kt * 64 + slot * 8;
        gload16(xh + goffA, (char*)sAh + q * 1024);
        gload16(xl + goffA, (char*)sAl + q * 1024);
        gload16(cTh + goffB, (char*)sBh + q * 1024);
        gload16(cTl + goffB, (char*)sBl + q * 1024);
      }
    } else {
#pragma unroll
      for (int i = 0; i < 8; ++i) {
        int e = i * 256 + tid, row = e >> 4, ch = e & 15;
        f16x4 hv, lv;
#pragma unroll
        for (int c = 0; c < 4; ++c) {
          f16 h, l;
          split16(av[i][c], h, l);
          hv[c] = h;
          lv[c] = l;
        }
        int boff = row * 128 + ((((ch >> 1) ^ (row & 7)) << 4)) + ((ch & 1) << 3);
        *(f16x4*)((char*)sAh + boff) = hv;
        *(f16x4*)((char*)sAl + boff) = lv;
      }
#pragma unroll
      for (int i = 0; i < 4; ++i) {
        int q = w * 4 + i;
        int s0 = q * 1024 + lane * 16;
        int row = s0 >> 7;
        int slot = ((s0 >> 4) & 7) ^ (row & 7);
        size_t goff = (size_t)(pb * 128 + row) * DIM + kt * 64 + slot * 8;
        gload16(cTh + goff, (char*)sBh + q * 1024);
        gload16(cTl + goff, (char*)sBl + q * 1024);
      }
      if (kt < 11) {
#pragma unroll
        for (int i = 0; i < 8; ++i) {
          int e = i * 256 + tid, row = e >> 4, ch = e & 15;
          av[i] = *(const f32x4*)(x + (size_t)(rb * 128 + row) * DIM +
                                  (kt + 1) * 64 + ch * 4);
        }
      }
    }
    __syncthreads();

#pragma unroll
    for (int k32 = 0; k32 < 2; ++k32) {
      f16x8 ah[4], al[4], bh[4], bl[4];
      int ksel = lane >> 4;
      int rsel = lane & 15;
#pragma unroll
      for (int m = 0; m < 4; ++m) {
        int row = wrow + m * 16 + rsel;
        int boff = row * 128 + (((k32 * 4 + ksel) ^ (row & 7)) << 4);
        ah[m] = *(const f16x8*)((const char*)sAh + boff);
        al[m] = *(const f16x8*)((const char*)sAl + boff);
      }
#pragma unroll
      for (int n = 0; n < 4; ++n) {
        int row = wcol + n * 16 + rsel;
        int boff = row * 128 + (((k32 * 4 + ksel) ^ (row & 7)) << 4);
        bh[n] = *(const f16x8*)((const char*)sBh + boff);
        bl[n] = *(const f16x8*)((const char*)sBl + boff);
      }
#pragma unroll
      for (int m = 0; m < 4; ++m)
#pragma unroll
        for (int n = 0; n < 4; ++n) {
          acc[m][n] =
              __builtin_amdgcn_mfma_f32_16x16x32_f16(ah[m], bh[n], acc[m][n], 0, 0, 0);
          accx[m][n] =
              __builtin_amdgcn_mfma_f32_16x16x32_f16(ah[m], bl[n], accx[m][n], 0, 0, 0);
          accx[m][n] =
              __builtin_amdgcn_mfma_f32_16x16x32_f16(al[m], bh[n], accx[m][n], 0, 0, 0);
        }
    }
  }

  __syncthreads();
  float* lv = (float*)lds;                 // [2][128]
  float* lsv = (float*)lds + 256;          // [2][128]
  int*   li = (int*)((float*)lds + 512);   // [2][128]

  int rsel = lane & 15;
  int colbase = pb * 128 + wcol + rsel;
  float cnv[4];
#pragma unroll
  for (int n = 0; n < 4; ++n) cnv[n] = cn[colbase + n * 16];
  int g4 = (lane >> 4) * 4;

#pragma unroll
  for (int m = 0; m < 4; ++m) {
#pragma unroll
    for (int j = 0; j < 4; ++j) {
      int trow = wrow + m * 16 + g4 + j;
      float xv = xn[rb * 128 + trow];
      float v1 = 0.0f, v2 = INFINITY;
      int i1 = 0;
#pragma unroll
      for (int n = 0; n < 4; ++n) {
        float dot = acc[m][n][j] + accx[m][n][j] * (1.0f / 4096.0f);
        float dd = (xv - 2.0f * dot) + cnv[n];
        int ci = colbase + n * 16;
        if (n == 0) { v1 = dd; i1 = ci; }
        else if (dd < v1) { v2 = v1; v1 = dd; i1 = ci; }
        else { v2 = fminf(v2, dd); }
      }
#pragma unroll
      for (int off = 1; off < 16; off <<= 1) {
        float ov1 = __shfl_xor(v1, off);
        float ov2 = __shfl_xor(v2, off);
        int oi1 = __shfl_xor(i1, off);
        if (ov1 < v1 || (ov1 == v1 && oi1 < i1)) {
          v2 = fminf(v1, ov2); v1 = ov1; i1 = oi1;
        } else {
          v2 = fminf(v2, ov1);
        }
      }
      if ((lane & 15) == 0) {
        lv[(w & 1) * 128 + trow] = v1;
        lsv[(w & 1) * 128 + trow] = v2;
        li[(w & 1) * 128 + trow] = i1;
      }
    }
  }
  __syncthreads();
  if (tid < 128) {
    float a1 = lv[tid], a2 = lsv[tid];
    int aj = li[tid];
    float b1 = lv[128 + tid], b2 = lsv[128 + tid];
    int bj = li[128 + tid];
    float v1, v2; int i1;
    if (b1 < a1 || (b1 == a1 && bj < aj)) { v1 = b1; i1 = bj; v2 = fminf(b2, a1); }
    else { v1 = a1; i1 = aj; v2 = fminf(a2, b1); }
    size_t o = (size_t)pb * N_ROWS + rb * 128 + tid;
    pmin[o] = v1;
    psec[o] = v2;
    pidx[o] = i1;
  }
}

// K4: merge 16 panel triples; write argmin; flag ambiguous rows (margin < TAU).
__global__ void merge_detect(const float* __restrict__ pmin,
                             const float* __restrict__ psec,
                             const int* __restrict__ pidx, int* __restrict__ out,
                             int* __restrict__ list, int* __restrict__ counter) {
  int n = blockIdx.x * 256 + threadIdx.x;
  float v1 = INFINITY, v2 = INFINITY;
  int i1 = 0x7fffffff;
  for (int p = 0; p < 16; ++p) {
    float a1 = pmin[(size_t)p * N_ROWS + n];
    float a2 = psec[(size_t)p * N_ROWS + n];
    int aj = pidx[(size_t)p * N_ROWS + n];
    if (a1 < v1 || (a1 == v1 && aj < i1)) {
      v2 = fminf(v1, a2); v1 = a1; i1 = aj;
    } else {
      v2 = fminf(v2, a1);
    }
  }
  out[n] = i1;
  if (v2 - v1 < TAU) {
    int idx = atomicAdd(counter, 1);
    if (idx < LISTCAP) list[idx] = n;
  }
}

// K5: float64 exact recheck for ambiguous rows — true distances.
__global__ __launch_bounds__(256) void exact_recheck64(
    const float* __restrict__ x, const float* __restrict__ cent,
    const double* __restrict__ cn64, const int* __restrict__ list,
    const int* __restrict__ counter, int* __restrict__ out) {
  __shared__ double xrow[DIM];   // 6 KB
  __shared__ double rv[256];
  __shared__ int ri[256];
  int b = blockIdx.x;
  if (b >= counter[0]) return;
  int n = list[b];
  int tid = threadIdx.x;
  double part = 0.0;
  for (int d = tid; d < DIM; d += 256) {
    double v = (double)x[(size_t)n * DIM + d];
    xrow[d] = v;
    part += v * v;
  }
  rv[tid] = part;
  __syncthreads();
  for (int s = 128; s > 0; s >>= 1) {
    if (tid < s) rv[tid] += rv[tid + s];
    __syncthreads();
  }
  double xn64 = rv[0];
  __syncthreads();
  double acc[8] = {0, 0, 0, 0, 0, 0, 0, 0};
  for (int d = 0; d < DIM; ++d) {
    double xv = xrow[d];
    const float* cp = cent + (size_t)d * K_C;
#pragma unroll
    for (int kk = 0; kk < 8; ++kk) {
      int k = tid + kk * 256;
      if (k < K_C) acc[kk] = fma(xv, (double)cp[k], acc[kk]);
    }
  }
  double bv = (double)INFINITY;
  int bi = 0x7fffffff;
#pragma unroll
  for (int kk = 0; kk < 8; ++kk) {
    int k = tid + kk * 256;
    if (k < K_C) {
      double dd = (xn64 - 2.0 * acc[kk]) + cn64[k];
      if (dd < bv) { bv = dd; bi = k; }  // k ascending -> first index kept
    }
  }
  rv[tid] = bv;
  ri[tid] = bi;
  __syncthreads();
  for (int s = 128; s > 0; s >>= 1) {
    if (tid < s) {
      double ov = rv[tid + s];
      int oi = ri[tid + s];
      if (ov < rv[tid] || (ov == rv[tid] && oi < ri[tid])) {
        rv[tid] = ov; ri[tid] = oi;
      }
    }
    __syncthreads();
  }
  if (tid == 0) out[n] = ri[0];
}

extern "C" void kernel_launch(void* const* d_in, const int* in_sizes, int n_in,
                              void* d_out, int out_size, void* d_ws, size_t ws_size,
                              hipStream_t stream) {
  const float* x = (const float*)d_in[0];
  const float* cent = (const float*)d_in[1];
  char* ws = (char*)d_ws;
  f16* cTh = (f16*)ws;
  f16* cTl = (f16*)(ws + OFF_CTL);
  float* cn = (float*)(ws + OFF_CN);
  float* xn = (float*)(ws + OFF_XN);
  float* pmin = (float*)(ws + OFF_PMIN);
  float* psec = (float*)(ws + OFF_PSEC);
  int* pidx = (int*)(ws + OFF_PIDX);
  int* counter = (int*)(ws + OFF_CNT);
  int* list = (int*)(ws + OFF_LIST);
  double* cn64 = (double*)(ws + OFF_CN64);
  f16* xh = (f16*)(ws + OFF_XH);
  f16* xl = (f16*)(ws + OFF_XL);

  bool pre = ws_size >= WS_NEED;

  hipMemsetAsync(counter, 0, 4, stream);
  prep_cn<<<8, 256, 0, stream>>>(cent, cn, cn64);
  prep_ct<<<dim3(32, 12), 256, 0, stream>>>(cent, cTh, cTl);
  xnorm_kernel<<<N_ROWS / 16, 256, 0, stream>>>(x, xn);
  if (pre) {
    prep_x<<<N_ROWS * DIM / (256 * 8), 256, 0, stream>>>(x, xh, xl);
    kmeans_main<1><<<16384, 256, 0, stream>>>(x, xh, xl, cTh, cTl, cn, xn,
                                              pmin, psec, pidx);
  } else {
    kmeans_main<0><<<16384, 256, 0, stream>>>(x, xh, xl, cTh, cTl, cn, xn,
                                              pmin, psec, pidx);
  }
  merge_detect<<<N_ROWS / 256, 256, 0, stream>>>(pmin, psec, pidx, (int*)d_out,
                                                 list, counter);
  exact_recheck64<<<LISTCAP, 256, 0, stream>>>(x, cent, cn64, list, counter,
                                               (int*)d_out);
}

// Round 7
// 1938.529 us; speedup vs baseline: 1.8818x; 1.7478x over previous
//
#include <hip/hip_runtime.h>
#include <hip/hip_bf16.h>

#define N_ROWS 131072
#define DIM    768
#define K_C    2000
#define K_PAD  2048
#define TAU    2e-2f
#define LISTCAP 4096

typedef _Float16 f16;
typedef _Float16 f16x4 __attribute__((ext_vector_type(4)));
typedef _Float16 f16x8 __attribute__((ext_vector_type(8)));
typedef float    f32x4 __attribute__((ext_vector_type(4)));

// ---- workspace layout (bytes) ----
#define OFF_CTL  3145728    // cTl  [2048][768] f16
#define OFF_CN   6291456    // cn   [2048] f32
#define OFF_XN   6299648    // xn   [131072] f32
#define OFF_PMIN 6823936    // pmin [16][131072] f32
#define OFF_PSEC 15212544   // psec [16][131072] f32
#define OFF_PIDX 23601152   // pidx [16][131072] i32
#define OFF_CNT  31989760   // counter (4B, padded)
#define OFF_LIST 31990016   // list [4096] i32
#define OFF_CN64 32006400   // cn64 [2048] f64
#define OFF_XH   32022784   // xh [131072][768] f16 (PRE path)
#define OFF_XL   233349376  // xl [131072][768] f16 (PRE path)
#define WS_NEED  434675968ULL

static __device__ __forceinline__ void gload16(const void* g, void* l) {
  __builtin_amdgcn_global_load_lds(
      (const __attribute__((address_space(1))) unsigned int*)g,
      (__attribute__((address_space(3))) unsigned int*)l, 16, 0, 0);
}

static __device__ __forceinline__ void split16(float v, f16& h, f16& l) {
  h = (f16)v;
  l = (f16)((v - (float)h) * 4096.0f);
}

// K1a: c_norm only (np axis-0 order: sequential over d; square rounded first)
// + fp64 c_norm for the exact recheck. Coalesced loads, no scatter stores.
__global__ void prep_cn(const float* __restrict__ cent, float* __restrict__ cn,
                        double* __restrict__ cn64) {
#pragma clang fp contract(off)
  int k = blockIdx.x * 256 + threadIdx.x;  // 0..2047
  float s = 0.0f;
  double s64 = 0.0;
  for (int d = 0; d < DIM; ++d) {
    float c = (k < K_C) ? cent[d * K_C + k] : 0.0f;
    float sq = c * c;
    s = s + sq;
    s64 += (double)c * (double)c;
  }
  cn[k] = (k < K_C) ? s : INFINITY;
  cn64[k] = (k < K_C) ? s64 : (double)INFINITY;
}

// K1b: centroid transpose + f16 hi/lo split via 64x64 LDS tile.
__global__ __launch_bounds__(256) void prep_ct(const float* __restrict__ cent,
                                               f16* __restrict__ cTh,
                                               f16* __restrict__ cTl) {
  __shared__ float ld[64][65];
  int k0 = blockIdx.x * 64;  // 32 blocks
  int d0 = blockIdx.y * 64;  // 12 blocks
  int tid = threadIdx.x;
#pragma unroll
  for (int it = 0; it < 16; ++it) {
    int idx = it * 256 + tid;
    int dd = idx >> 6, kk = idx & 63;
    int k = k0 + kk;
    ld[dd][kk] = (k < K_C) ? cent[(size_t)(d0 + dd) * K_C + k] : 0.0f;
  }
  __syncthreads();
#pragma unroll
  for (int it = 0; it < 16; ++it) {
    int idx = it * 256 + tid;
    int kk = idx >> 6, dd = idx & 63;
    float v = ld[dd][kk];
    f16 h, l;
    split16(v, h, l);
    size_t o = (size_t)(k0 + kk) * DIM + d0 + dd;
    cTh[o] = h;
    cTl[o] = l;
  }
}

// K1c: x -> f16 hi/lo (PRE path). 8 floats/thread, all coalesced.
__global__ __launch_bounds__(256) void prep_x(const float* __restrict__ x,
                                              f16* __restrict__ xh,
                                              f16* __restrict__ xl) {
  size_t t = (size_t)blockIdx.x * 256 + threadIdx.x;
  const f32x4* src = (const f32x4*)(x + t * 8);
  f32x4 a = src[0], b = src[1];
  f16x8 hv, lv;
#pragma unroll
  for (int j = 0; j < 4; ++j) {
    f16 h, l;
    split16(a[j], h, l);
    hv[j] = h; lv[j] = l;
    split16(b[j], h, l);
    hv[4 + j] = h; lv[4 + j] = l;
  }
  *(f16x8*)(xh + t * 8) = hv;
  *(f16x8*)(xl + t * 8) = lv;
}

// K2: x_norm per numpy FLOAT_pairwise_sum(768) scalar semantics.
__global__ __launch_bounds__(256) void xnorm_kernel(const float* __restrict__ x,
                                                    float* __restrict__ xn) {
#pragma clang fp contract(off)
  __shared__ __align__(16) float buf[16 * DIM];  // 48 KB, 16 rows
  int row0 = blockIdx.x * 16;
  int tid = threadIdx.x;
  const f32x4* src = (const f32x4*)(x + (size_t)row0 * DIM);
  f32x4* dst = (f32x4*)buf;
#pragma unroll
  for (int c = 0; c < 12; ++c) dst[c * 256 + tid] = src[c * 256 + tid];
  __syncthreads();
  int w = tid >> 6, lane = tid & 63;
  int b = lane >> 3, j = lane & 7;
#pragma unroll
  for (int rr = 0; rr < 4; ++rr) {
    int r = w * 4 + rr;
    const float* a = buf + r * DIM + 96 * b + j;
    float v0 = a[0];
    float acc = v0 * v0;
#pragma unroll
    for (int t = 1; t < 12; ++t) {
      float q = a[8 * t];
      float s = q * q;
      acc = acc + s;
    }
    float v = acc;
    { float o = __shfl_xor(v, 1);  v = v + o; }
    { float o = __shfl_xor(v, 2);  v = v + o; }
    { float o = __shfl_xor(v, 4);  v = v + o; }
    { float o = __shfl_xor(v, 8);  v = v + o; }
    { float o = __shfl_xor(v, 16); v = v + o; }
    { float o = __shfl_xor(v, 32); v = v + o; }
    if (lane == 0) xn[row0 + r] = v;
  }
}

// K3: split-fp16 MFMA GEMM + fused per-panel best/second/argmin.
template <int PRE>
__global__ __launch_bounds__(256, 2) void kmeans_main(
    const float* __restrict__ x, const f16* __restrict__ xh,
    const f16* __restrict__ xl, const f16* __restrict__ cTh,
    const f16* __restrict__ cTl, const float* __restrict__ cn,
    const float* __restrict__ xn, float* __restrict__ pmin,
    float* __restrict__ psec, int* __restrict__ pidx) {
  __shared__ __align__(16) f16 lds[32768];  // 64 KiB
  f16* sAh = lds;
  f16* sAl = lds + 8192;
  f16* sBh = lds + 16384;
  f16* sBl = lds + 24576;

  int d0 = blockIdx.x;
  int g  = (d0 & 7) * 2048 + (d0 >> 3);  // XCD-grouped
  int pb = g & 15;
  int rb = g >> 4;

  int tid  = threadIdx.x;
  int w    = tid >> 6;
  int lane = tid & 63;
  int wrow = (w >> 1) * 64;
  int wcol = (w & 1) * 64;

  f32x4 acc[4][4] = {};
  f32x4 accx[4][4] = {};

  f32x4 av[8];
  if constexpr (!PRE) {
#pragma unroll
    for (int i = 0; i < 8; ++i) {
      int e = i * 256 + tid, row = e >> 4, ch = e & 15;
      av[i] = *(const f32x4*)(x + (size_t)(rb * 128 + row) * DIM + ch * 4);
    }
  }

  for (int kt = 0; kt < 12; ++kt) {
    __syncthreads();
    if constexpr (PRE) {
#pragma unroll
      for (int i = 0; i < 4; ++i) {
        int q = w * 4 + i;
        int s0 = q * 1024 + lane * 16;
        int row = s0 >> 7;
        int slot = ((s0 >> 4) & 7) ^ (row & 7);
        size_t goffA = (size_t)(rb * 128 + row) * DIM + kt * 64 + slot * 8;
        size_t goffB = (size_t)(pb * 128 + row) * DIM + kt * 64 + slot * 8;
        gload16(xh + goffA, (char*)sAh + q * 1024);
        gload16(xl + goffA, (char*)sAl + q * 1024);
        gload16(cTh + goffB, (char*)sBh + q * 1024);
        gload16(cTl + goffB, (char*)sBl + q * 1024);
      }
    } else {
#pragma unroll
      for (int i = 0; i < 8; ++i) {
        int e = i * 256 + tid, row = e >> 4, ch = e & 15;
        f16x4 hv, lv;
#pragma unroll
        for (int c = 0; c < 4; ++c) {
          f16 h, l;
          split16(av[i][c], h, l);
          hv[c] = h;
          lv[c] = l;
        }
        int boff = row * 128 + ((((ch >> 1) ^ (row & 7)) << 4)) + ((ch & 1) << 3);
        *(f16x4*)((char*)sAh + boff) = hv;
        *(f16x4*)((char*)sAl + boff) = lv;
      }
#pragma unroll
      for (int i = 0; i < 4; ++i) {
        int q = w * 4 + i;
        int s0 = q * 1024 + lane * 16;
        int row = s0 >> 7;
        int slot = ((s0 >> 4) & 7) ^ (row & 7);
        size_t goff = (size_t)(pb * 128 + row) * DIM + kt * 64 + slot * 8;
        gload16(cTh + goff, (char*)sBh + q * 1024);
        gload16(cTl + goff, (char*)sBl + q * 1024);
      }
      if (kt < 11) {
#pragma unroll
        for (int i = 0; i < 8; ++i) {
          int e = i * 256 + tid, row = e >> 4, ch = e & 15;
          av[i] = *(const f32x4*)(x + (size_t)(rb * 128 + row) * DIM +
                                  (kt + 1) * 64 + ch * 4);
        }
      }
    }
    __syncthreads();

#pragma unroll
    for (int k32 = 0; k32 < 2; ++k32) {
      f16x8 ah[4], al[4], bh[4], bl[4];
      int ksel = lane >> 4;
      int rsel = lane & 15;
#pragma unroll
      for (int m = 0; m < 4; ++m) {
        int row = wrow + m * 16 + rsel;
        int boff = row * 128 + (((k32 * 4 + ksel) ^ (row & 7)) << 4);
        ah[m] = *(const f16x8*)((const char*)sAh + boff);
        al[m] = *(const f16x8*)((const char*)sAl + boff);
      }
#pragma unroll
      for (int n = 0; n < 4; ++n) {
        int row = wcol + n * 16 + rsel;
        int boff = row * 128 + (((k32 * 4 + ksel) ^ (row & 7)) << 4);
        bh[n] = *(const f16x8*)((const char*)sBh + boff);
        bl[n] = *(const f16x8*)((const char*)sBl + boff);
      }
#pragma unroll
      for (int m = 0; m < 4; ++m)
#pragma unroll
        for (int n = 0; n < 4; ++n) {
          acc[m][n] =
              __builtin_amdgcn_mfma_f32_16x16x32_f16(ah[m], bh[n], acc[m][n], 0, 0, 0);
          accx[m][n] =
              __builtin_amdgcn_mfma_f32_16x16x32_f16(ah[m], bl[n], accx[m][n], 0, 0, 0);
          accx[m][n] =
              __builtin_amdgcn_mfma_f32_16x16x32_f16(al[m], bh[n], accx[m][n], 0, 0, 0);
        }
    }
  }

  __syncthreads();
  float* lv = (float*)lds;                 // [2][128]
  float* lsv = (float*)lds + 256;          // [2][128]
  int*   li = (int*)((float*)lds + 512);   // [2][128]

  int rsel = lane & 15;
  int colbase = pb * 128 + wcol + rsel;
  float cnv[4];
#pragma unroll
  for (int n = 0; n < 4; ++n) cnv[n] = cn[colbase + n * 16];
  int g4 = (lane >> 4) * 4;

#pragma unroll
  for (int m = 0; m < 4; ++m) {
#pragma unroll
    for (int j = 0; j < 4; ++j) {
      int trow = wrow + m * 16 + g4 + j;
      float xv = xn[rb * 128 + trow];
      float v1 = 0.0f, v2 = INFINITY;
      int i1 = 0;
#pragma unroll
      for (int n = 0; n < 4; ++n) {
        float dot = acc[m][n][j] + accx[m][n][j] * (1.0f / 4096.0f);
        float dd = (xv - 2.0f * dot) + cnv[n];
        int ci = colbase + n * 16;
        if (n == 0) { v1 = dd; i1 = ci; }
        else if (dd < v1) { v2 = v1; v1 = dd; i1 = ci; }
        else { v2 = fminf(v2, dd); }
      }
#pragma unroll
      for (int off = 1; off < 16; off <<= 1) {
        float ov1 = __shfl_xor(v1, off);
        float ov2 = __shfl_xor(v2, off);
        int oi1 = __shfl_xor(i1, off);
        if (ov1 < v1 || (ov1 == v1 && oi1 < i1)) {
          v2 = fminf(v1, ov2); v1 = ov1; i1 = oi1;
        } else {
          v2 = fminf(v2, ov1);
        }
      }
      if ((lane & 15) == 0) {
        lv[(w & 1) * 128 + trow] = v1;
        lsv[(w & 1) * 128 + trow] = v2;
        li[(w & 1) * 128 + trow] = i1;
      }
    }
  }
  __syncthreads();
  if (tid < 128) {
    float a1 = lv[tid], a2 = lsv[tid];
    int aj = li[tid];
    float b1 = lv[128 + tid], b2 = lsv[128 + tid];
    int bj = li[128 + tid];
    float v1, v2; int i1;
    if (b1 < a1 || (b1 == a1 && bj < aj)) { v1 = b1; i1 = bj; v2 = fminf(b2, a1); }
    else { v1 = a1; i1 = aj; v2 = fminf(a2, b1); }
    size_t o = (size_t)pb * N_ROWS + rb * 128 + tid;
    pmin[o] = v1;
    psec[o] = v2;
    pidx[o] = i1;
  }
}

// K4: merge 16 panel triples; write argmin; flag ambiguous rows (margin < TAU).
__global__ void merge_detect(const float* __restrict__ pmin,
                             const float* __restrict__ psec,
                             const int* __restrict__ pidx, int* __restrict__ out,
                             int* __restrict__ list, int* __restrict__ counter) {
  int n = blockIdx.x * 256 + threadIdx.x;
  float v1 = INFINITY, v2 = INFINITY;
  int i1 = 0x7fffffff;
  for (int p = 0; p < 16; ++p) {
    float a1 = pmin[(size_t)p * N_ROWS + n];
    float a2 = psec[(size_t)p * N_ROWS + n];
    int aj = pidx[(size_t)p * N_ROWS + n];
    if (a1 < v1 || (a1 == v1 && aj < i1)) {
      v2 = fminf(v1, a2); v1 = a1; i1 = aj;
    } else {
      v2 = fminf(v2, a1);
    }
  }
  out[n] = i1;
  if (v2 - v1 < TAU) {
    int idx = atomicAdd(counter, 1);
    if (idx < LISTCAP) list[idx] = n;
  }
}

// K5: float64 exact recheck for ambiguous rows — true distances.
// NAMED scalar f64 accumulators (a0..a7) so they live in VGPRs (r6 showed
// the acc[8] array + per-iter k<K_C branch spilled to scratch: VGPR=20,
// 1.6 ms). k7 clamped instead of branched; candidates k = tid + 256*j.
__global__ __launch_bounds__(256) void exact_recheck64(
    const float* __restrict__ x, const float* __restrict__ cent,
    const double* __restrict__ cn64, const int* __restrict__ list,
    const int* __restrict__ counter, int* __restrict__ out) {
  __shared__ __align__(16) float xrow[DIM];  // 3 KB
  __shared__ double rv[256];
  __shared__ int ri[256];
  int b = blockIdx.x;
  if (b >= counter[0]) return;
  int n = list[b];
  int tid = threadIdx.x;
  double part = 0.0;
  for (int d = tid; d < DIM; d += 256) {
    float v = x[(size_t)n * DIM + d];
    xrow[d] = v;
    part += (double)v * (double)v;
  }
  rv[tid] = part;
  __syncthreads();
  for (int s = 128; s > 0; s >>= 1) {
    if (tid < s) rv[tid] += rv[tid + s];
    __syncthreads();
  }
  double xn64 = rv[0];
  __syncthreads();

  int k7 = tid + 1792;
  int k7c = (k7 < K_C) ? k7 : (K_C - 1);  // clamp; result discarded if OOB
  double a0 = 0, a1 = 0, a2 = 0, a3 = 0, a4 = 0, a5 = 0, a6 = 0, a7 = 0;
#pragma unroll 4
  for (int d = 0; d < DIM; ++d) {
    double xv = (double)xrow[d];
    const float* cp = cent + (size_t)d * K_C + tid;
    a0 = fma(xv, (double)cp[0], a0);
    a1 = fma(xv, (double)cp[256], a1);
    a2 = fma(xv, (double)cp[512], a2);
    a3 = fma(xv, (double)cp[768], a3);
    a4 = fma(xv, (double)cp[1024], a4);
    a5 = fma(xv, (double)cp[1280], a5);
    a6 = fma(xv, (double)cp[1536], a6);
    a7 = fma(xv, (double)(cp[k7c - tid]), a7);
  }

  double bv = (double)INFINITY;
  int bi = 0x7fffffff;
  double dots[8] = {a0, a1, a2, a3, a4, a5, a6, a7};
#pragma unroll
  for (int j = 0; j < 8; ++j) {
    int k = tid + j * 256;
    if (k < K_C) {
      double dd = (xn64 - 2.0 * dots[j]) + cn64[k];
      if (dd < bv) { bv = dd; bi = k; }  // k ascending -> first index kept
    }
  }
  rv[tid] = bv;
  ri[tid] = bi;
  __syncthreads();
  for (int s = 128; s > 0; s >>= 1) {
    if (tid < s) {
      double ov = rv[tid + s];
      int oi = ri[tid + s];
      if (ov < rv[tid] || (ov == rv[tid] && oi < ri[tid])) {
        rv[tid] = ov; ri[tid] = oi;
      }
    }
    __syncthreads();
  }
  if (tid == 0) out[n] = ri[0];
}

extern "C" void kernel_launch(void* const* d_in, const int* in_sizes, int n_in,
                              void* d_out, int out_size, void* d_ws, size_t ws_size,
                              hipStream_t stream) {
  const float* x = (const float*)d_in[0];
  const float* cent = (const float*)d_in[1];
  char* ws = (char*)d_ws;
  f16* cTh = (f16*)ws;
  f16* cTl = (f16*)(ws + OFF_CTL);
  float* cn = (float*)(ws + OFF_CN);
  float* xn = (float*)(ws + OFF_XN);
  float* pmin = (float*)(ws + OFF_PMIN);
  float* psec = (float*)(ws + OFF_PSEC);
  int* pidx = (int*)(ws + OFF_PIDX);
  int* counter = (int*)(ws + OFF_CNT);
  int* list = (int*)(ws + OFF_LIST);
  double* cn64 = (double*)(ws + OFF_CN64);
  f16* xh = (f16*)(ws + OFF_XH);
  f16* xl = (f16*)(ws + OFF_XL);

  bool pre = ws_size >= WS_NEED;

  hipMemsetAsync(counter, 0, 4, stream);
  prep_cn<<<8, 256, 0, stream>>>(cent, cn, cn64);
  prep_ct<<<dim3(32, 12), 256, 0, stream>>>(cent, cTh, cTl);
  xnorm_kernel<<<N_ROWS / 16, 256, 0, stream>>>(x, xn);
  if (pre) {
    prep_x<<<N_ROWS * DIM / (256 * 8), 256, 0, stream>>>(x, xh, xl);
    kmeans_main<1><<<16384, 256, 0, stream>>>(x, xh, xl, cTh, cTl, cn, xn,
                                              pmin, psec, pidx);
  } else {
    kmeans_main<0><<<16384, 256, 0, stream>>>(x, xh, xl, cTh, cTl, cn, xn,
                                              pmin, psec, pidx);
  }
  merge_detect<<<N_ROWS / 256, 256, 0, stream>>>(pmin, psec, pidx, (int*)d_out,
                                                 list, counter);
  exact_recheck64<<<LISTCAP, 256, 0, stream>>>(x, cent, cn64, list, counter,
                                               (int*)d_out);
}

// Round 8
// 1769.773 us; speedup vs baseline: 2.0613x; 1.0954x over previous
//
#include <hip/hip_runtime.h>
#include <hip/hip_bf16.h>

#define N_ROWS 131072
#define DIM    768
#define K_C    2000
#define K_PAD  2048
#define TAU    2e-2f
#define LISTCAP 4096

typedef _Float16 f16;
typedef _Float16 f16x4 __attribute__((ext_vector_type(4)));
typedef _Float16 f16x8 __attribute__((ext_vector_type(8)));
typedef float    f32x4 __attribute__((ext_vector_type(4)));

// ---- workspace layout (bytes) ----
#define OFF_CTL  3145728    // cTl  [2048][768] f16
#define OFF_CN   6291456    // cn   [2048] f32
#define OFF_XN   6299648    // xn   [131072] f32
#define OFF_PMIN 6823936    // pmin [16][131072] f32
#define OFF_PSEC 15212544   // psec [16][131072] f32
#define OFF_PIDX 23601152   // pidx [16][131072] i32
#define OFF_CNT  31989760   // counter (4B, padded)
#define OFF_LIST 31990016   // list [4096] i32
#define OFF_CN64 32006400   // cn64 [2048] f64
#define OFF_XH   32022784   // xh [131072][768] f16
#define OFF_XL   233349376  // xl [131072][768] f16
#define WS_NEED  434675968ULL

static __device__ __forceinline__ void gload16(const void* g, void* l) {
  __builtin_amdgcn_global_load_lds(
      (const __attribute__((address_space(1))) unsigned int*)g,
      (__attribute__((address_space(3))) unsigned int*)l, 16, 0, 0);
}

static __device__ __forceinline__ void split16(float v, f16& h, f16& l) {
  h = (f16)v;
  l = (f16)((v - (float)h) * 4096.0f);
}

// K1a: fp32 c_norm (np axis-0 sequential order) + fp64 c_norm for recheck.
__global__ void prep_cn(const float* __restrict__ cent, float* __restrict__ cn,
                        double* __restrict__ cn64) {
#pragma clang fp contract(off)
  int k = blockIdx.x * 256 + threadIdx.x;  // 0..2047
  float s = 0.0f;
  double s64 = 0.0;
  for (int d = 0; d < DIM; ++d) {
    float c = (k < K_C) ? cent[d * K_C + k] : 0.0f;
    float sq = c * c;
    s = s + sq;
    s64 += (double)c * (double)c;
  }
  cn[k] = (k < K_C) ? s : INFINITY;
  cn64[k] = (k < K_C) ? s64 : (double)INFINITY;
}

// K1b: centroid transpose + f16 hi/lo split via 64x64 LDS tile.
__global__ __launch_bounds__(256) void prep_ct(const float* __restrict__ cent,
                                               f16* __restrict__ cTh,
                                               f16* __restrict__ cTl) {
  __shared__ float ld[64][65];
  int k0 = blockIdx.x * 64;  // 32 blocks
  int d0 = blockIdx.y * 64;  // 12 blocks
  int tid = threadIdx.x;
#pragma unroll
  for (int it = 0; it < 16; ++it) {
    int idx = it * 256 + tid;
    int dd = idx >> 6, kk = idx & 63;
    int k = k0 + kk;
    ld[dd][kk] = (k < K_C) ? cent[(size_t)(d0 + dd) * K_C + k] : 0.0f;
  }
  __syncthreads();
#pragma unroll
  for (int it = 0; it < 16; ++it) {
    int idx = it * 256 + tid;
    int kk = idx >> 6, dd = idx & 63;
    float v = ld[dd][kk];
    f16 h, l;
    split16(v, h, l);
    size_t o = (size_t)(k0 + kk) * DIM + d0 + dd;
    cTh[o] = h;
    cTl[o] = l;
  }
}

// K2: x_norm (numpy FLOAT_pairwise_sum(768) scalar semantics) FUSED with
// x -> f16 hi/lo split (both stream x once; saves a full 402 MB pass).
__global__ __launch_bounds__(256) void xnorm_prepx(const float* __restrict__ x,
                                                   float* __restrict__ xn,
                                                   f16* __restrict__ xh,
                                                   f16* __restrict__ xl) {
#pragma clang fp contract(off)
  __shared__ __align__(16) float buf[16 * DIM];  // 48 KB, 16 rows
  int row0 = blockIdx.x * 16;
  int tid = threadIdx.x;
  const f32x4* src = (const f32x4*)(x + (size_t)row0 * DIM);
  f32x4* dst = (f32x4*)buf;
#pragma unroll
  for (int c = 0; c < 12; ++c) {
    f32x4 v = src[c * 256 + tid];
    dst[c * 256 + tid] = v;
    f16x4 hv, lv;
#pragma unroll
    for (int j = 0; j < 4; ++j) {
      f16 h, l;
      split16(v[j], h, l);
      hv[j] = h;
      lv[j] = l;
    }
    size_t o = (size_t)row0 * DIM + (size_t)(c * 256 + tid) * 4;
    *(f16x4*)(xh + o) = hv;
    *(f16x4*)(xl + o) = lv;
  }
  __syncthreads();
  int w = tid >> 6, lane = tid & 63;
  int b = lane >> 3, j = lane & 7;
#pragma unroll
  for (int rr = 0; rr < 4; ++rr) {
    int r = w * 4 + rr;
    const float* a = buf + r * DIM + 96 * b + j;
    float v0 = a[0];
    float acc = v0 * v0;
#pragma unroll
    for (int t = 1; t < 12; ++t) {
      float q = a[8 * t];
      float s = q * q;
      acc = acc + s;
    }
    float v = acc;
    { float o = __shfl_xor(v, 1);  v = v + o; }
    { float o = __shfl_xor(v, 2);  v = v + o; }
    { float o = __shfl_xor(v, 4);  v = v + o; }
    { float o = __shfl_xor(v, 8);  v = v + o; }
    { float o = __shfl_xor(v, 16); v = v + o; }
    { float o = __shfl_xor(v, 32); v = v + o; }
    if (lane == 0) xn[row0 + r] = v;
  }
}

// K3: split-fp16 MFMA GEMM + fused argmin. T3/T4 pipeline: BK=32,
// double-buffered LDS (64 KiB total -> 2 blocks/CU), 2-deep prefetch,
// counted vmcnt(8) across raw barriers (never drained to 0 in steady
// state), setprio around the MFMA cluster.
// LDS byte map: Ah@0, Al@16384, Bh@32768, Bl@49152; per-array buf stride 8192.
// Swizzle: slot' = slot ^ W(row), W(r) = (r&3)^((r>>2)&3)  (max 2-way = free).
#define STAGE(bufb, kt)                                                        \
  {                                                                            \
    int ko = (kt) * 32 + ke;                                                   \
    size_t ra0 = (size_t)(rb * 128 + c0 * 16 + rl) * DIM + ko;                 \
    size_t ra1 = (size_t)(rb * 128 + c1 * 16 + rl) * DIM + ko;                 \
    size_t rb0 = (size_t)(pb * 128 + c0 * 16 + rl) * DIM + ko;                 \
    size_t rb1 = (size_t)(pb * 128 + c1 * 16 + rl) * DIM + ko;                 \
    gload16(xh + ra0, ldsb + (bufb) + c0 * 1024);                              \
    gload16(xh + ra1, ldsb + (bufb) + c1 * 1024);                              \
    gload16(xl + ra0, ldsb + 16384 + (bufb) + c0 * 1024);                      \
    gload16(xl + ra1, ldsb + 16384 + (bufb) + c1 * 1024);                      \
    gload16(cTh + rb0, ldsb + 32768 + (bufb) + c0 * 1024);                     \
    gload16(cTh + rb1, ldsb + 32768 + (bufb) + c1 * 1024);                     \
    gload16(cTl + rb0, ldsb + 49152 + (bufb) + c0 * 1024);                     \
    gload16(cTl + rb1, ldsb + 49152 + (bufb) + c1 * 1024);                     \
  }

__global__ __launch_bounds__(256, 2) void kmeans_main(
    const f16* __restrict__ xh, const f16* __restrict__ xl,
    const f16* __restrict__ cTh, const f16* __restrict__ cTl,
    const float* __restrict__ cn, const float* __restrict__ xn,
    float* __restrict__ pmin, float* __restrict__ psec,
    int* __restrict__ pidx) {
  __shared__ __align__(16) f16 lds[32768];  // 64 KiB
  char* ldsb = (char*)lds;

  int d0 = blockIdx.x;
  int g  = (d0 & 7) * 2048 + (d0 >> 3);  // XCD-grouped
  int pb = g & 15;
  int rb = g >> 4;

  int tid  = threadIdx.x;
  int w    = tid >> 6;
  int lane = tid & 63;
  int wrow = (w >> 1) * 64;
  int wcol = (w & 1) * 64;

  // staging per-lane constants: chunk = 1 KB = 16 rows x 64 B
  int rl  = lane >> 2;                         // row within chunk
  int sw3 = ((lane >> 2) ^ (lane >> 4)) & 3;   // W(row) seen by this lane
  int ke  = (((lane & 3) ^ sw3) << 3);         // inverse-swizzled k-elem ofs
  int c0 = w * 2, c1 = w * 2 + 1;              // this wave's chunks

  // read-side per-lane constants
  int rsel = lane & 15;
  int ksel = lane >> 4;
  int rdslot = (((ksel ^ ((rsel & 3) ^ ((rsel >> 2) & 3)))) << 4);

  f32x4 acc[4][4] = {};
  f32x4 accx[4][4] = {};

  STAGE(0, 0);
  STAGE(8192, 1);

  for (int kt = 0; kt < 24; ++kt) {
    int bufb = (kt & 1) * 8192;
    if (kt < 23) {
      asm volatile("s_waitcnt vmcnt(8)" ::: "memory");  // kt's loads landed
    } else {
      asm volatile("s_waitcnt vmcnt(0)" ::: "memory");  // tail drain
    }
    __builtin_amdgcn_sched_barrier(0);
    __builtin_amdgcn_s_barrier();
    __builtin_amdgcn_sched_barrier(0);

    f16x8 ah[4], al[4], bh[4], bl[4];
#pragma unroll
    for (int m = 0; m < 4; ++m) {
      int boff = bufb + (wrow + m * 16 + rsel) * 64 + rdslot;
      ah[m] = *(const f16x8*)(ldsb + boff);
      al[m] = *(const f16x8*)(ldsb + 16384 + boff);
    }
#pragma unroll
    for (int n = 0; n < 4; ++n) {
      int boff = bufb + (wcol + n * 16 + rsel) * 64 + rdslot;
      bh[n] = *(const f16x8*)(ldsb + 32768 + boff);
      bl[n] = *(const f16x8*)(ldsb + 49152 + boff);
    }
    __builtin_amdgcn_sched_barrier(0);
    asm volatile("s_waitcnt lgkmcnt(0)" ::: "memory");  // frags in VGPRs
    __builtin_amdgcn_sched_barrier(0);
    __builtin_amdgcn_s_barrier();  // all waves done reading buf[cur]
    __builtin_amdgcn_sched_barrier(0);

    if (kt < 22) STAGE(bufb, kt + 2);  // overwrite freed buffer; in flight
                                       // across next barriers (vmcnt counted)
    __builtin_amdgcn_s_setprio(1);
#pragma unroll
    for (int m = 0; m < 4; ++m)
#pragma unroll
      for (int n = 0; n < 4; ++n) {
        acc[m][n] =
            __builtin_amdgcn_mfma_f32_16x16x32_f16(ah[m], bh[n], acc[m][n], 0, 0, 0);
        accx[m][n] =
            __builtin_amdgcn_mfma_f32_16x16x32_f16(ah[m], bl[n], accx[m][n], 0, 0, 0);
        accx[m][n] =
            __builtin_amdgcn_mfma_f32_16x16x32_f16(al[m], bh[n], accx[m][n], 0, 0, 0);
      }
    __builtin_amdgcn_s_setprio(0);
  }

  __syncthreads();  // full drain; LDS reused below
  float* lv = (float*)lds;                 // [2][128]
  float* lsv = (float*)lds + 256;          // [2][128]
  int*   li = (int*)((float*)lds + 512);   // [2][128]

  int colbase = pb * 128 + wcol + rsel;
  float cnv[4];
#pragma unroll
  for (int n = 0; n < 4; ++n) cnv[n] = cn[colbase + n * 16];
  int g4 = (lane >> 4) * 4;

#pragma unroll
  for (int m = 0; m < 4; ++m) {
#pragma unroll
    for (int j = 0; j < 4; ++j) {
      int trow = wrow + m * 16 + g4 + j;
      float xv = xn[rb * 128 + trow];
      float v1 = 0.0f, v2 = INFINITY;
      int i1 = 0;
#pragma unroll
      for (int n = 0; n < 4; ++n) {
        float dot = acc[m][n][j] + accx[m][n][j] * (1.0f / 4096.0f);
        float dd = (xv - 2.0f * dot) + cnv[n];
        int ci = colbase + n * 16;
        if (n == 0) { v1 = dd; i1 = ci; }
        else if (dd < v1) { v2 = v1; v1 = dd; i1 = ci; }
        else { v2 = fminf(v2, dd); }
      }
#pragma unroll
      for (int off = 1; off < 16; off <<= 1) {
        float ov1 = __shfl_xor(v1, off);
        float ov2 = __shfl_xor(v2, off);
        int oi1 = __shfl_xor(i1, off);
        if (ov1 < v1 || (ov1 == v1 && oi1 < i1)) {
          v2 = fminf(v1, ov2); v1 = ov1; i1 = oi1;
        } else {
          v2 = fminf(v2, ov1);
        }
      }
      if ((lane & 15) == 0) {
        lv[(w & 1) * 128 + trow] = v1;
        lsv[(w & 1) * 128 + trow] = v2;
        li[(w & 1) * 128 + trow] = i1;
      }
    }
  }
  __syncthreads();
  if (tid < 128) {
    float a1 = lv[tid], a2 = lsv[tid];
    int aj = li[tid];
    float b1 = lv[128 + tid], b2 = lsv[128 + tid];
    int bj = li[128 + tid];
    float v1, v2; int i1;
    if (b1 < a1 || (b1 == a1 && bj < aj)) { v1 = b1; i1 = bj; v2 = fminf(b2, a1); }
    else { v1 = a1; i1 = aj; v2 = fminf(a2, b1); }
    size_t o = (size_t)pb * N_ROWS + rb * 128 + tid;
    pmin[o] = v1;
    psec[o] = v2;
    pidx[o] = i1;
  }
}

// K4: merge 16 panel triples; write argmin; flag ambiguous rows (margin < TAU).
__global__ void merge_detect(const float* __restrict__ pmin,
                             const float* __restrict__ psec,
                             const int* __restrict__ pidx, int* __restrict__ out,
                             int* __restrict__ list, int* __restrict__ counter) {
  int n = blockIdx.x * 256 + threadIdx.x;
  float v1 = INFINITY, v2 = INFINITY;
  int i1 = 0x7fffffff;
  for (int p = 0; p < 16; ++p) {
    float a1 = pmin[(size_t)p * N_ROWS + n];
    float a2 = psec[(size_t)p * N_ROWS + n];
    int aj = pidx[(size_t)p * N_ROWS + n];
    if (a1 < v1 || (a1 == v1 && aj < i1)) {
      v2 = fminf(v1, a2); v1 = a1; i1 = aj;
    } else {
      v2 = fminf(v2, a1);
    }
  }
  out[n] = i1;
  if (v2 - v1 < TAU) {
    int idx = atomicAdd(counter, 1);
    if (idx < LISTCAP) list[idx] = n;
  }
}

// K5: float64 exact recheck for ambiguous rows — NAMED scalar f64
// accumulators (array+branch form spilled to scratch in r6: VGPR=20, 1.6ms).
__global__ __launch_bounds__(256) void exact_recheck64(
    const float* __restrict__ x, const float* __restrict__ cent,
    const double* __restrict__ cn64, const int* __restrict__ list,
    const int* __restrict__ counter, int* __restrict__ out) {
  __shared__ __align__(16) float xrow[DIM];  // 3 KB
  __shared__ double rv[256];
  __shared__ int ri[256];
  int b = blockIdx.x;
  if (b >= counter[0]) return;
  int n = list[b];
  int tid = threadIdx.x;
  double part = 0.0;
  for (int d = tid; d < DIM; d += 256) {
    float v = x[(size_t)n * DIM + d];
    xrow[d] = v;
    part += (double)v * (double)v;
  }
  rv[tid] = part;
  __syncthreads();
  for (int s = 128; s > 0; s >>= 1) {
    if (tid < s) rv[tid] += rv[tid + s];
    __syncthreads();
  }
  double xn64 = rv[0];
  __syncthreads();

  int k7 = tid + 1792;
  int k7c = (k7 < K_C) ? k7 : (K_C - 1);  // clamp; result discarded if OOB
  double a0 = 0, a1 = 0, a2 = 0, a3 = 0, a4 = 0, a5 = 0, a6 = 0, a7 = 0;
#pragma unroll 4
  for (int d = 0; d < DIM; ++d) {
    double xv = (double)xrow[d];
    const float* cp = cent + (size_t)d * K_C + tid;
    a0 = fma(xv, (double)cp[0], a0);
    a1 = fma(xv, (double)cp[256], a1);
    a2 = fma(xv, (double)cp[512], a2);
    a3 = fma(xv, (double)cp[768], a3);
    a4 = fma(xv, (double)cp[1024], a4);
    a5 = fma(xv, (double)cp[1280], a5);
    a6 = fma(xv, (double)cp[1536], a6);
    a7 = fma(xv, (double)(cp[k7c - tid]), a7);
  }

  double bv = (double)INFINITY;
  int bi = 0x7fffffff;
  double dots[8] = {a0, a1, a2, a3, a4, a5, a6, a7};
#pragma unroll
  for (int j = 0; j < 8; ++j) {
    int k = tid + j * 256;
    if (k < K_C) {
      double dd = (xn64 - 2.0 * dots[j]) + cn64[k];
      if (dd < bv) { bv = dd; bi = k; }  // k ascending -> first index kept
    }
  }
  rv[tid] = bv;
  ri[tid] = bi;
  __syncthreads();
  for (int s = 128; s > 0; s >>= 1) {
    if (tid < s) {
      double ov = rv[tid + s];
      int oi = ri[tid + s];
      if (ov < rv[tid] || (ov == rv[tid] && oi < ri[tid])) {
        rv[tid] = ov; ri[tid] = oi;
      }
    }
    __syncthreads();
  }
  if (tid == 0) out[n] = ri[0];
}

extern "C" void kernel_launch(void* const* d_in, const int* in_sizes, int n_in,
                              void* d_out, int out_size, void* d_ws, size_t ws_size,
                              hipStream_t stream) {
  const float* x = (const float*)d_in[0];
  const float* cent = (const float*)d_in[1];
  char* ws = (char*)d_ws;
  f16* cTh = (f16*)ws;
  f16* cTl = (f16*)(ws + OFF_CTL);
  float* cn = (float*)(ws + OFF_CN);
  float* xn = (float*)(ws + OFF_XN);
  float* pmin = (float*)(ws + OFF_PMIN);
  float* psec = (float*)(ws + OFF_PSEC);
  int* pidx = (int*)(ws + OFF_PIDX);
  int* counter = (int*)(ws + OFF_CNT);
  int* list = (int*)(ws + OFF_LIST);
  double* cn64 = (double*)(ws + OFF_CN64);
  f16* xh = (f16*)(ws + OFF_XH);
  f16* xl = (f16*)(ws + OFF_XL);

  hipMemsetAsync(counter, 0, 4, stream);
  prep_cn<<<8, 256, 0, stream>>>(cent, cn, cn64);
  prep_ct<<<dim3(32, 12), 256, 0, stream>>>(cent, cTh, cTl);
  xnorm_prepx<<<N_ROWS / 16, 256, 0, stream>>>(x, xn, xh, xl);
  kmeans_main<<<16384, 256, 0, stream>>>(xh, xl, cTh, cTl, cn, xn,
                                         pmin, psec, pidx);
  merge_detect<<<N_ROWS / 256, 256, 0, stream>>>(pmin, psec, pidx, (int*)d_out,
                                                 list, counter);
  exact_recheck64<<<LISTCAP, 256, 0, stream>>>(x, cent, cn64, list, counter,
                                               (int*)d_out);
}

// Round 9
// 1260.340 us; speedup vs baseline: 2.8944x; 1.4042x over previous
//
#include <hip/hip_runtime.h>
#include <hip/hip_bf16.h>

#define N_ROWS 131072
#define DIM    768
#define K_C    2000
#define K_PAD  2048
#define TAU    0.2f
#define LISTCAP 8192

typedef _Float16 f16;
typedef _Float16 f16x4 __attribute__((ext_vector_type(4)));
typedef _Float16 f16x8 __attribute__((ext_vector_type(8)));
typedef float    f32x4 __attribute__((ext_vector_type(4)));

// ---- workspace layout (bytes) ----
#define OFF_CN   6291456    // cn   [2048] f32
#define OFF_XN   6299648    // xn   [131072] f32
#define OFF_PMIN 6823936    // pmin [16][131072] f32
#define OFF_PSEC 15212544   // psec [16][131072] f32
#define OFF_PIDX 23601152   // pidx [16][131072] i32
#define OFF_CNT  31989760   // counter
#define OFF_LIST 31990016   // list [8192] i32
#define OFF_CN64 32022784   // cn64 [2048] f64
#define OFF_XH   32039168   // xh [131072][768] f16

static __device__ __forceinline__ void gload16(const void* g, void* l) {
  __builtin_amdgcn_global_load_lds(
      (const __attribute__((address_space(1))) unsigned int*)g,
      (__attribute__((address_space(3))) unsigned int*)l, 16, 0, 0);
}

// K1a: fp32 c_norm (np axis-0 sequential order) + fp64 c_norm for recheck.
__global__ void prep_cn(const float* __restrict__ cent, float* __restrict__ cn,
                        double* __restrict__ cn64) {
#pragma clang fp contract(off)
  int k = blockIdx.x * 256 + threadIdx.x;  // 0..2047
  float s = 0.0f;
  double s64 = 0.0;
  for (int d = 0; d < DIM; ++d) {
    float c = (k < K_C) ? cent[d * K_C + k] : 0.0f;
    float sq = c * c;
    s = s + sq;
    s64 += (double)c * (double)c;
  }
  cn[k] = (k < K_C) ? s : INFINITY;
  cn64[k] = (k < K_C) ? s64 : (double)INFINITY;
}

// K1b: centroid transpose to f16 (hi only) via 64x64 LDS tile.
__global__ __launch_bounds__(256) void prep_ct(const float* __restrict__ cent,
                                               f16* __restrict__ cTh) {
  __shared__ float ld[64][65];
  int k0 = blockIdx.x * 64;  // 32 blocks
  int d0 = blockIdx.y * 64;  // 12 blocks
  int tid = threadIdx.x;
#pragma unroll
  for (int it = 0; it < 16; ++it) {
    int idx = it * 256 + tid;
    int dd = idx >> 6, kk = idx & 63;
    int k = k0 + kk;
    ld[dd][kk] = (k < K_C) ? cent[(size_t)(d0 + dd) * K_C + k] : 0.0f;
  }
  __syncthreads();
#pragma unroll
  for (int it = 0; it < 16; ++it) {
    int idx = it * 256 + tid;
    int kk = idx >> 6, dd = idx & 63;
    cTh[(size_t)(k0 + kk) * DIM + d0 + dd] = (f16)ld[dd][kk];
  }
}

// K2: x_norm (numpy FLOAT_pairwise_sum(768) scalar semantics) fused with
// x -> f16 (hi only).
__global__ __launch_bounds__(256) void xnorm_prepx(const float* __restrict__ x,
                                                   float* __restrict__ xn,
                                                   f16* __restrict__ xh) {
#pragma clang fp contract(off)
  __shared__ __align__(16) float buf[16 * DIM];  // 48 KB, 16 rows
  int row0 = blockIdx.x * 16;
  int tid = threadIdx.x;
  const f32x4* src = (const f32x4*)(x + (size_t)row0 * DIM);
  f32x4* dst = (f32x4*)buf;
#pragma unroll
  for (int c = 0; c < 12; ++c) {
    f32x4 v = src[c * 256 + tid];
    dst[c * 256 + tid] = v;
    f16x4 hv;
#pragma unroll
    for (int j = 0; j < 4; ++j) hv[j] = (f16)v[j];
    *(f16x4*)(xh + (size_t)row0 * DIM + (size_t)(c * 256 + tid) * 4) = hv;
  }
  __syncthreads();
  int w = tid >> 6, lane = tid & 63;
  int b = lane >> 3, j = lane & 7;
#pragma unroll
  for (int rr = 0; rr < 4; ++rr) {
    int r = w * 4 + rr;
    const float* a = buf + r * DIM + 96 * b + j;
    float v0 = a[0];
    float acc = v0 * v0;
#pragma unroll
    for (int t = 1; t < 12; ++t) {
      float q = a[8 * t];
      float s = q * q;
      acc = acc + s;
    }
    float v = acc;
    { float o = __shfl_xor(v, 1);  v = v + o; }
    { float o = __shfl_xor(v, 2);  v = v + o; }
    { float o = __shfl_xor(v, 4);  v = v + o; }
    { float o = __shfl_xor(v, 8);  v = v + o; }
    { float o = __shfl_xor(v, 16); v = v + o; }
    { float o = __shfl_xor(v, 32); v = v + o; }
    if (lane == 0) xn[row0 + r] = v;
  }
}

// K3: f16 MFMA GEMM (hi-only; tau-gate covers the f16 error) + fused argmin.
// BK=64, r7-PROVEN LDS layout (128-B rows, slot ^= row&7 -> 0 bank conflicts
// measured r5-r7; r8's 64-B-row variant measured 1e8), double-buffered,
// counted vmcnt(8), setprio MFMA cluster.
// LDS map: A bufs @0/@16384, B bufs @32768/@49152 (16 KB each).
#define STAGE(bufb, ktv)                                                       \
  do {                                                                         \
    _Pragma("unroll") for (int i_ = 0; i_ < 4; ++i_) {                         \
      int q_ = w * 4 + i_;                                                     \
      int s0_ = q_ * 1024 + lane * 16;                                         \
      int row_ = s0_ >> 7;                                                     \
      int sl_ = ((s0_ >> 4) & 7) ^ (row_ & 7);                                 \
      size_t ga_ = (size_t)(rb * 128 + row_) * DIM + (ktv) * 64 + sl_ * 8;     \
      size_t gb_ = (size_t)(pb * 128 + row_) * DIM + (ktv) * 64 + sl_ * 8;     \
      gload16(xh + ga_, ldsb + (bufb) + q_ * 1024);                            \
      gload16(cTh + gb_, ldsb + 32768 + (bufb) + q_ * 1024);                   \
    }                                                                          \
  } while (0)

__global__ __launch_bounds__(256, 2) void kmeans_main(
    const f16* __restrict__ xh, const f16* __restrict__ cTh,
    const float* __restrict__ cn, const float* __restrict__ xn,
    float* __restrict__ pmin, float* __restrict__ psec,
    int* __restrict__ pidx) {
  __shared__ __align__(16) f16 lds[32768];  // 64 KiB
  char* ldsb = (char*)lds;

  int d0 = blockIdx.x;
  int g  = (d0 & 7) * 2048 + (d0 >> 3);  // XCD-grouped
  int pb = g & 15;
  int rb = g >> 4;

  int tid  = threadIdx.x;
  int w    = tid >> 6;
  int lane = tid & 63;
  int wrow = (w >> 1) * 64;
  int wcol = (w & 1) * 64;

  int rsel = lane & 15;
  int ksel = lane >> 4;
  int rs0 = ((ksel ^ (rsel & 7))) << 4;        // k32=0 slot byte-offset
  int rs1 = (((4 + ksel) ^ (rsel & 7))) << 4;  // k32=1

  f32x4 acc[4][4] = {};

  STAGE(0, 0);
  STAGE(16384, 1);

  for (int kt = 0; kt < 12; ++kt) {
    int bufb = (kt & 1) * 16384;
    if (kt < 11) {
      asm volatile("s_waitcnt vmcnt(8)" ::: "memory");  // tile kt landed
    } else {
      asm volatile("s_waitcnt vmcnt(0)" ::: "memory");
    }
    __builtin_amdgcn_sched_barrier(0);
    __builtin_amdgcn_s_barrier();
    __builtin_amdgcn_sched_barrier(0);

    f16x8 ah[2][4], bh[2][4];
#pragma unroll
    for (int m = 0; m < 4; ++m) {
      int rbase = bufb + (wrow + m * 16 + rsel) * 128;
      ah[0][m] = *(const f16x8*)(ldsb + rbase + rs0);
      ah[1][m] = *(const f16x8*)(ldsb + rbase + rs1);
    }
#pragma unroll
    for (int n = 0; n < 4; ++n) {
      int rbase = bufb + 32768 + (wcol + n * 16 + rsel) * 128;
      bh[0][n] = *(const f16x8*)(ldsb + rbase + rs0);
      bh[1][n] = *(const f16x8*)(ldsb + rbase + rs1);
    }
    __builtin_amdgcn_sched_barrier(0);
    asm volatile("s_waitcnt lgkmcnt(0)" ::: "memory");
    __builtin_amdgcn_sched_barrier(0);
    __builtin_amdgcn_s_barrier();  // all waves done reading buf[cur]
    __builtin_amdgcn_sched_barrier(0);

    if (kt < 10) STAGE(bufb, kt + 2);  // in flight across next barriers

    __builtin_amdgcn_s_setprio(1);
#pragma unroll
    for (int k32 = 0; k32 < 2; ++k32)
#pragma unroll
      for (int m = 0; m < 4; ++m)
#pragma unroll
        for (int n = 0; n < 4; ++n)
          acc[m][n] = __builtin_amdgcn_mfma_f32_16x16x32_f16(
              ah[k32][m], bh[k32][n], acc[m][n], 0, 0, 0);
    __builtin_amdgcn_s_setprio(0);
  }

  __syncthreads();  // drain; LDS reused below
  float* lv = (float*)lds;                 // [2][128]
  float* lsv = (float*)lds + 256;          // [2][128]
  int*   li = (int*)((float*)lds + 512);   // [2][128]

  int colbase = pb * 128 + wcol + rsel;
  float cnv[4];
#pragma unroll
  for (int n = 0; n < 4; ++n) cnv[n] = cn[colbase + n * 16];
  int g4 = ksel * 4;

#pragma unroll
  for (int m = 0; m < 4; ++m) {
#pragma unroll
    for (int j = 0; j < 4; ++j) {
      int trow = wrow + m * 16 + g4 + j;
      float xv = xn[rb * 128 + trow];
      float v1 = 0.0f, v2 = INFINITY;
      int i1 = 0;
#pragma unroll
      for (int n = 0; n < 4; ++n) {
        float dd = (xv - 2.0f * acc[m][n][j]) + cnv[n];
        int ci = colbase + n * 16;
        if (n == 0) { v1 = dd; i1 = ci; }
        else if (dd < v1) { v2 = v1; v1 = dd; i1 = ci; }
        else { v2 = fminf(v2, dd); }
      }
#pragma unroll
      for (int off = 1; off < 16; off <<= 1) {
        float ov1 = __shfl_xor(v1, off);
        float ov2 = __shfl_xor(v2, off);
        int oi1 = __shfl_xor(i1, off);
        if (ov1 < v1 || (ov1 == v1 && oi1 < i1)) {
          v2 = fminf(v1, ov2); v1 = ov1; i1 = oi1;
        } else {
          v2 = fminf(v2, ov1);
        }
      }
      if ((lane & 15) == 0) {
        lv[(w & 1) * 128 + trow] = v1;
        lsv[(w & 1) * 128 + trow] = v2;
        li[(w & 1) * 128 + trow] = i1;
      }
    }
  }
  __syncthreads();
  if (tid < 128) {
    float a1 = lv[tid], a2 = lsv[tid];
    int aj = li[tid];
    float b1 = lv[128 + tid], b2 = lsv[128 + tid];
    int bj = li[128 + tid];
    float v1, v2; int i1;
    if (b1 < a1 || (b1 == a1 && bj < aj)) { v1 = b1; i1 = bj; v2 = fminf(b2, a1); }
    else { v1 = a1; i1 = aj; v2 = fminf(a2, b1); }
    size_t o = (size_t)pb * N_ROWS + rb * 128 + tid;
    pmin[o] = v1;
    psec[o] = v2;
    pidx[o] = i1;
  }
}

// K4: merge 16 panel triples; flag ambiguous rows (margin < TAU).
__global__ void merge_detect(const float* __restrict__ pmin,
                             const float* __restrict__ psec,
                             const int* __restrict__ pidx, int* __restrict__ out,
                             int* __restrict__ list, int* __restrict__ counter) {
  int n = blockIdx.x * 256 + threadIdx.x;
  float v1 = INFINITY, v2 = INFINITY;
  int i1 = 0x7fffffff;
  for (int p = 0; p < 16; ++p) {
    float a1 = pmin[(size_t)p * N_ROWS + n];
    float a2 = psec[(size_t)p * N_ROWS + n];
    int aj = pidx[(size_t)p * N_ROWS + n];
    if (a1 < v1 || (a1 == v1 && aj < i1)) {
      v2 = fminf(v1, a2); v1 = a1; i1 = aj;
    } else {
      v2 = fminf(v2, a1);
    }
  }
  out[n] = i1;
  if (v2 - v1 < TAU) {
    int idx = atomicAdd(counter, 1);
    if (idx < LISTCAP) list[idx] = n;
  }
}

// K5: float64 exact recheck for ambiguous rows — NAMED scalar f64
// accumulators (array+branch form spilled to scratch in r6).
__global__ __launch_bounds__(256) void exact_recheck64(
    const float* __restrict__ x, const float* __restrict__ cent,
    const double* __restrict__ cn64, const int* __restrict__ list,
    const int* __restrict__ counter, int* __restrict__ out) {
  __shared__ __align__(16) float xrow[DIM];
  __shared__ double rv[256];
  __shared__ int ri[256];
  int b = blockIdx.x;
  if (b >= counter[0]) return;
  int n = list[b];
  int tid = threadIdx.x;
  double part = 0.0;
  for (int d = tid; d < DIM; d += 256) {
    float v = x[(size_t)n * DIM + d];
    xrow[d] = v;
    part += (double)v * (double)v;
  }
  rv[tid] = part;
  __syncthreads();
  for (int s = 128; s > 0; s >>= 1) {
    if (tid < s) rv[tid] += rv[tid + s];
    __syncthreads();
  }
  double xn64 = rv[0];
  __syncthreads();

  int k7 = tid + 1792;
  int k7c = (k7 < K_C) ? k7 : (K_C - 1);
  double a0 = 0, a1 = 0, a2 = 0, a3 = 0, a4 = 0, a5 = 0, a6 = 0, a7 = 0;
#pragma unroll 4
  for (int d = 0; d < DIM; ++d) {
    double xv = (double)xrow[d];
    const float* cp = cent + (size_t)d * K_C + tid;
    a0 = fma(xv, (double)cp[0], a0);
    a1 = fma(xv, (double)cp[256], a1);
    a2 = fma(xv, (double)cp[512], a2);
    a3 = fma(xv, (double)cp[768], a3);
    a4 = fma(xv, (double)cp[1024], a4);
    a5 = fma(xv, (double)cp[1280], a5);
    a6 = fma(xv, (double)cp[1536], a6);
    a7 = fma(xv, (double)(cp[k7c - tid]), a7);
  }

  double bv = (double)INFINITY;
  int bi = 0x7fffffff;
  double dots[8] = {a0, a1, a2, a3, a4, a5, a6, a7};
#pragma unroll
  for (int j = 0; j < 8; ++j) {
    int k = tid + j * 256;
    if (k < K_C) {
      double dd = (xn64 - 2.0 * dots[j]) + cn64[k];
      if (dd < bv) { bv = dd; bi = k; }  // k ascending -> first index kept
    }
  }
  rv[tid] = bv;
  ri[tid] = bi;
  __syncthreads();
  for (int s = 128; s > 0; s >>= 1) {
    if (tid < s) {
      double ov = rv[tid + s];
      int oi = ri[tid + s];
      if (ov < rv[tid] || (ov == rv[tid] && oi < ri[tid])) {
        rv[tid] = ov; ri[tid] = oi;
      }
    }
    __syncthreads();
  }
  if (tid == 0) out[n] = ri[0];
}

extern "C" void kernel_launch(void* const* d_in, const int* in_sizes, int n_in,
                              void* d_out, int out_size, void* d_ws, size_t ws_size,
                              hipStream_t stream) {
  const float* x = (const float*)d_in[0];
  const float* cent = (const float*)d_in[1];
  char* ws = (char*)d_ws;
  f16* cTh = (f16*)ws;
  float* cn = (float*)(ws + OFF_CN);
  float* xn = (float*)(ws + OFF_XN);
  float* pmin = (float*)(ws + OFF_PMIN);
  float* psec = (float*)(ws + OFF_PSEC);
  int* pidx = (int*)(ws + OFF_PIDX);
  int* counter = (int*)(ws + OFF_CNT);
  int* list = (int*)(ws + OFF_LIST);
  double* cn64 = (double*)(ws + OFF_CN64);
  f16* xh = (f16*)(ws + OFF_XH);

  hipMemsetAsync(counter, 0, 4, stream);
  prep_cn<<<8, 256, 0, stream>>>(cent, cn, cn64);
  prep_ct<<<dim3(32, 12), 256, 0, stream>>>(cent, cTh);
  xnorm_prepx<<<N_ROWS / 16, 256, 0, stream>>>(x, xn, xh);
  kmeans_main<<<16384, 256, 0, stream>>>(xh, cTh, cn, xn, pmin, psec, pidx);
  merge_detect<<<N_ROWS / 256, 256, 0, stream>>>(pmin, psec, pidx, (int*)d_out,
                                                 list, counter);
  exact_recheck64<<<LISTCAP, 256, 0, stream>>>(x, cent, cn64, list, counter,
                                               (int*)d_out);
}